// Round 1
// baseline (692.557 us; speedup 1.0000x reference)
//
#include <hip/hip_runtime.h>
#include <cstdint>
#include <cstddef>

// GRU (reset_after) + dense(1)+sigmoid, masked by per-batch length t.
// One block per batch (512 blocks, 192 threads = 3 waves).
// Lane j owns gate-column j: U[:,j] (64) + W[:,j] (24) in registers.
// wave0: z-cols 0..63, wave1: r-cols 64..127, wave2: c-cols 128..191 (+ h update + output dot).
// h broadcast via LDS; x staged in LDS in 64-step chunks (register-prefetched).
// Early exit at s==t[b]; tail of output row is constant fill.

#define NTHREADS 192

__global__ __launch_bounds__(NTHREADS, 2) void gru_fused_kernel(
    const float* __restrict__ xg,      // (512,1024,24)
    const int*   __restrict__ tg,      // (512,)  (int32 per harness convention)
    const float* __restrict__ Wg,      // (24,192)
    const float* __restrict__ Ug,      // (64,192)
    const float* __restrict__ bg,      // (2,192)
    const float* __restrict__ Wdg,     // (64,1)
    const float* __restrict__ bdg,     // (1,)
    float*       __restrict__ outg)    // (512,1024)
{
    const int b   = blockIdx.x;
    const int tid = threadIdx.x;

    __shared__ __align__(16) float x_lds[1536];   // 64 steps x 24 floats
    __shared__ __align__(16) float h_lds[64];
    __shared__ float z_lds[64];
    __shared__ float r_lds[64];
    __shared__ float last_lds;

    const int   t    = tg[b];
    float*      outb = outg + (size_t)b * 1024;
    const float bdv  = bdg[0];

    if (t > 0) {
        // ---- weight preload (coalesced across lanes; L2/L3-hot after first blocks) ----
        float Ureg[64];
        #pragma unroll
        for (int k = 0; k < 64; ++k) Ureg[k] = Ug[k * 192 + tid];
        float Wreg[24];
        #pragma unroll
        for (int d = 0; d < 24; ++d) Wreg[d] = Wg[d * 192 + tid];
        const float b0j = bg[tid];
        const float b1j = bg[192 + tid];
        const float wdj = (tid >= 128) ? Wdg[tid - 128] : 0.f;

        const float* xb = xg + (size_t)b * 24576;   // 1024*24

        // ---- prologue: stage chunk 0 into LDS, zero h ----
        const float4* xsrc = (const float4*)xb;
        float4 pf0 = xsrc[tid * 2];
        float4 pf1 = xsrc[tid * 2 + 1];
        float4* x_lds4 = (float4*)x_lds;
        x_lds4[tid * 2]     = pf0;
        x_lds4[tid * 2 + 1] = pf1;
        if (tid < 64) h_lds[tid] = 0.f;
        __syncthreads();
        // issue prefetch for chunk 1 (latency hidden under ~64 steps of compute)
        if (64 < t) {
            const float4* xn = (const float4*)(xb + 1536);
            pf0 = xn[tid * 2];
            pf1 = xn[tid * 2 + 1];
        }

        float pout = 0.f;   // wave2: deferred per-step output partial

        for (int s = 0; s < t; ++s) {
            const int c = s & 63;

            // ---- chunk boundary: commit prefetched x, start next prefetch ----
            if (c == 0 && s > 0) {
                // all x_lds reads of the previous chunk completed before the
                // previous step's barriers -> safe to overwrite now
                x_lds4[tid * 2]     = pf0;
                x_lds4[tid * 2 + 1] = pf1;
                __syncthreads();
                const int nc = (s >> 6) + 1;
                if (nc * 64 < t) {
                    const float4* xn = (const float4*)(xb + nc * 1536);
                    pf0 = xn[tid * 2];
                    pf1 = xn[tid * 2 + 1];
                }
            }

            // ---- deferred output reduce for step s-1 (wave2 only; independent of
            //      this step's chain -> compiler interleaves with matvec below) ----
            if (s > 0 && tid >= 128) {
                float tot = pout;
                #pragma unroll
                for (int m = 1; m < 64; m <<= 1) tot += __shfl_xor(tot, m, 64);
                if (tid == 191) outb[s - 1] = 1.f / (1.f + __expf(-(tot + bdv)));
            }

            // ---- phase 1 (all waves): broadcast-read h, register matvecs ----
            float4 h4[16];
            #pragma unroll
            for (int i = 0; i < 16; ++i) h4[i] = ((const float4*)h_lds)[i];

            float a0 = 0.f, a1 = 0.f, a2 = 0.f, a3 = 0.f;
            #pragma unroll
            for (int i = 0; i < 16; ++i) {
                a0 += h4[i].x * Ureg[4 * i + 0];
                a1 += h4[i].y * Ureg[4 * i + 1];
                a2 += h4[i].z * Ureg[4 * i + 2];
                a3 += h4[i].w * Ureg[4 * i + 3];
            }
            const float acc = (a0 + a1) + (a2 + a3) + b1j;   // h-part + recurrent bias

            const float4* xr4 = (const float4*)(x_lds + c * 24);
            float x0 = 0.f, x1 = 0.f, x2 = 0.f, x3 = 0.f;
            #pragma unroll
            for (int i = 0; i < 6; ++i) {
                const float4 xv = xr4[i];
                x0 += xv.x * Wreg[4 * i + 0];
                x1 += xv.y * Wreg[4 * i + 1];
                x2 += xv.z * Wreg[4 * i + 2];
                x3 += xv.w * Wreg[4 * i + 3];
            }
            const float xacc = (x0 + x1) + (x2 + x3) + b0j;  // x-part + input bias

            // ---- gates: z (wave0), r (wave1) ----
            if (tid < 128) {
                const float pre = acc + xacc;
                const float g = 1.f / (1.f + __expf(-pre));
                if (tid < 64) z_lds[tid] = g;
                else          r_lds[tid - 64] = g;
            }
            __syncthreads();   // BAR1: z,r visible; all h/x reads complete

            // ---- wave2: candidate, state update, output partial ----
            if (tid >= 128) {
                const int jj = tid - 128;
                const float rr = r_lds[jj];
                const float zz = z_lds[jj];
                const float ho = h_lds[jj];
                // tanh(y) = 1 - 2/(1+exp(2y))  (saturates correctly at +-inf)
                const float cg = 1.f - 2.f / (1.f + __expf(2.f * (xacc + rr * acc)));
                const float hn = zz * ho + (1.f - zz) * cg;
                h_lds[jj] = hn;
                pout = hn * wdj;
            }
            __syncthreads();   // BAR2: h' visible for next step
        }

        // ---- final step's output + constant tail fill ----
        if (tid >= 128) {
            float tot = pout;
            #pragma unroll
            for (int m = 1; m < 64; m <<= 1) tot += __shfl_xor(tot, m, 64);
            if (tid == 191) {
                const float o = 1.f / (1.f + __expf(-(tot + bdv)));
                outb[t - 1] = o;
                last_lds = o;
            }
        }
        __syncthreads();
        const float fill = last_lds;
        for (int i = t + tid; i < 1024; i += NTHREADS) outb[i] = fill;
    } else {
        // t == 0: h stays zero for the whole row -> out = sigmoid(bd)
        const float fill = 1.f / (1.f + __expf(-bdv));
        for (int i = tid; i < 1024; i += NTHREADS) outb[i] = fill;
    }
}

extern "C" void kernel_launch(void* const* d_in, const int* in_sizes, int n_in,
                              void* d_out, int out_size, void* d_ws, size_t ws_size,
                              hipStream_t stream) {
    (void)in_sizes; (void)n_in; (void)d_ws; (void)ws_size; (void)out_size;
    const float* x  = (const float*)d_in[0];
    const int*   t  = (const int*)d_in[1];
    const float* W  = (const float*)d_in[2];
    const float* U  = (const float*)d_in[3];
    const float* bb = (const float*)d_in[4];
    const float* Wd = (const float*)d_in[5];
    const float* bd = (const float*)d_in[6];
    float* out = (float*)d_out;

    hipLaunchKernelGGL(gru_fused_kernel, dim3(512), dim3(NTHREADS), 0, stream,
                       x, t, W, U, bb, Wd, bd, out);
}